// Round 5
// baseline (142.488 us; speedup 1.0000x reference)
//
#include <hip/hip_runtime.h>
#include <math.h>

// BEV deformable attention encoder, layer l = L-1 only.
// Round 5: k_cpb_mfma v3 — one block per gj-column; layer-1 folded into
// per-block LDS tables a[ix][k], c[iy][k] (h0 = relu(a+c)); register live-set
// cut to ~116 (r4: ~160 incl. AGPR overflow -> 23% occupancy + accvgpr churn).
// __launch_bounds__(256,4) targets 4 waves/SIMD. Rest unchanged from round 4.

#define NP 1600   // 40*40 query pixels
#define NJ 100    // 10*10 kv pixels

typedef __bf16 bf16x8 __attribute__((ext_vector_type(8)));
typedef float  f32x4  __attribute__((ext_vector_type(4)));
typedef float  f32x2  __attribute__((ext_vector_type(2)));

// ---------------- grouped 1x1 conv (q): 8 groups, cin/g=32, cout/g=64 ------
__global__ __launch_bounds__(256) void k_conv1x1(
    const float* __restrict__ x, const float* __restrict__ w,
    float* __restrict__ out) {
  int b = blockIdx.x;
  int g = b / 40;
  int r = b - g * 40;
  int oc = r / 5;
  int p0 = (r - oc * 5) * 320;
  int co0 = g * 64 + oc * 8;
  const float* xg = x + g * 32 * NP;
  const float* wr = w + co0 * 32;   // block-uniform -> scalar loads
  for (int p = p0 + threadIdx.x; p < p0 + 320; p += 256) {
    float acc[8];
#pragma unroll
    for (int o = 0; o < 8; ++o) acc[o] = 0.f;
#pragma unroll
    for (int ci = 0; ci < 32; ++ci) {
      float xv = xg[ci * NP + p];
#pragma unroll
      for (int o = 0; o < 8; ++o) acc[o] = fmaf(wr[o * 32 + ci], xv, acc[o]);
    }
#pragma unroll
    for (int o = 0; o < 8; ++o) out[(co0 + o) * NP + p] = acc[o];
  }
}

// ------------- offset depthwise 6x6 s4 pad1 + bias + exact GELU ------------
__global__ __launch_bounds__(256) void k_off_dw(
    const float* __restrict__ q, const float* __restrict__ w1,
    const float* __restrict__ b1, float* __restrict__ off1) {
  int idx = blockIdx.x * 256 + threadIdx.x;   // 51200 exactly
  int j = idx % 100;
  int d = (idx / 100) & 63;
  int bg = idx / 6400;
  int oy = j / 10, ox = j - (j / 10) * 10;
  float acc = b1[d];
  const float* qc = q + (bg * 64 + d) * NP;
#pragma unroll
  for (int ky = 0; ky < 6; ++ky) {
    int iy = oy * 4 - 1 + ky;
    if (iy < 0 || iy >= 40) continue;
#pragma unroll
    for (int kx = 0; kx < 6; ++kx) {
      int ix = ox * 4 - 1 + kx;
      if (ix < 0 || ix >= 40) continue;
      acc = fmaf(w1[d * 36 + ky * 6 + kx], qc[iy * 40 + ix], acc);
    }
  }
  off1[idx] = 0.5f * acc * (1.0f + erff(acc * 0.70710678118654752440f));
}

// ------- fused: offset 1x1 + tanh*4 + grid + sample + k/v conv + tables ----
// One WAVE per (g,j): 800 waves = 200 blocks x 256.
__global__ __launch_bounds__(256) void k_off_pw_kv(
    const float* __restrict__ off1, const float* __restrict__ w2,
    const float* __restrict__ x, const float* __restrict__ wk,
    const float* __restrict__ wv, float* __restrict__ kout,
    float* __restrict__ vout, float* __restrict__ su_tab,
    float* __restrict__ sv_tab) {
  int lane = threadIdx.x & 63;
  int wid = blockIdx.x * 4 + (threadIdx.x >> 6);
  int g = wid / 100;
  int j = wid - g * 100;
  const float* wkr = wk + (g * 64 + lane) * 32;
  const float* wvr = wv + (g * 64 + lane) * 32;
  float wkreg[32], wvreg[32];
#pragma unroll
  for (int q4 = 0; q4 < 8; ++q4) {
    f32x4 a = *(const f32x4*)(wkr + q4 * 4);
    f32x4 b = *(const f32x4*)(wvr + q4 * 4);
#pragma unroll
    for (int e = 0; e < 4; ++e) { wkreg[q4 * 4 + e] = a[e]; wvreg[q4 * 4 + e] = b[e]; }
  }
  // pointwise offset conv + tanh*4
  float o = off1[(g * 64 + lane) * 100 + j];
  float px = w2[lane] * o, py = w2[64 + lane] * o;
#pragma unroll
  for (int m = 1; m < 64; m <<= 1) {
    px += __shfl_xor(px, m);
    py += __shfl_xor(py, m);
  }
  float ax = tanhf(px) * 4.f;
  float ay = tanhf(py) * 4.f;
  float vx = (float)(j - (j / 10) * 10) + ax;
  float vy = (float)(j / 10) + ay;
  float g0 = 2.f * vx / 9.f - 1.f;
  float g1 = 2.f * vy / 9.f - 1.f;
  // CPB signed-log coordinate tables: one entry per (gj, coord 0..39)
  if (lane < 40) {
    float qc = (float)lane * (2.f / 39.f) - 1.f;
    float u = qc - g0;
    float vv = qc - g1;
    su_tab[wid * 40 + lane] = copysignf(log1pf(fabsf(u)), u);
    sv_tab[wid * 40 + lane] = copysignf(log1pf(fabsf(vv)), vv);
  }
  // bilinear sample (uniform weights; lanes<32 gather), then k/v conv
  float gx = ((g0 + 1.f) * 40.f - 1.f) * 0.5f;
  float gy = ((g1 + 1.f) * 40.f - 1.f) * 0.5f;
  float x0f = floorf(gx), y0f = floorf(gy);
  float wx = gx - x0f, wy = gy - y0f;
  bool mx0 = (x0f >= 0.f) && (x0f <= 39.f);
  bool mx1 = (x0f + 1.f >= 0.f) && (x0f + 1.f <= 39.f);
  bool my0 = (y0f >= 0.f) && (y0f <= 39.f);
  bool my1 = (y0f + 1.f >= 0.f) && (y0f + 1.f <= 39.f);
  int ix0 = (int)fminf(fmaxf(x0f, 0.f), 39.f);
  int ix1 = (int)fminf(fmaxf(x0f + 1.f, 0.f), 39.f);
  int iy0 = (int)fminf(fmaxf(y0f, 0.f), 39.f);
  int iy1 = (int)fminf(fmaxf(y0f + 1.f, 0.f), 39.f);
  float w00 = (1.f - wx) * (1.f - wy) * ((mx0 && my0) ? 1.f : 0.f);
  float w10 = wx * (1.f - wy) * ((mx1 && my0) ? 1.f : 0.f);
  float w01 = (1.f - wx) * wy * ((mx0 && my1) ? 1.f : 0.f);
  float w11 = wx * wy * ((mx1 && my1) ? 1.f : 0.f);
  int b00 = iy0 * 40 + ix0, b10 = iy0 * 40 + ix1;
  int b01 = iy1 * 40 + ix0, b11 = iy1 * 40 + ix1;
  float kvc = 0.f;
  if (lane < 32) {
    const float* xc = x + (g * 32 + lane) * NP;
    kvc = w00 * xc[b00] + w10 * xc[b10] + w01 * xc[b01] + w11 * xc[b11];
  }
  float kacc = 0.f, vacc = 0.f;
#pragma unroll
  for (int c = 0; c < 32; ++c) {
    float kvb = __shfl(kvc, c);
    kacc = fmaf(wkreg[c], kvb, kacc);
    vacc = fmaf(wvreg[c], kvb, vacc);
  }
  kout[(g * 64 + lane) * 100 + j] = kacc;
  vout[(g * 64 + lane) * 100 + j] = vacc;
}

// ---------------- CPB bias MLP v3: LDS layer-1 tables + split-bf16 MFMA ----
// One block per column gj (800 blocks, 4 waves). LDS: a[ix][k], c[iy][k]
// (stride 68 floats: 16B-aligned rows, <=2-way banks). h0 = relu(a+c).
// Wave w owns tiles w*25..w*25+24 (tile = 16 consecutive i).
__global__ __launch_bounds__(256, 4) void k_cpb_mfma(
    const float* __restrict__ su_tab, const float* __restrict__ sv_tab,
    const float* __restrict__ w0, const float* __restrict__ b0,
    const float* __restrict__ w1, const float* __restrict__ b1v,
    const float* __restrict__ w2, const float* __restrict__ b2,
    float* __restrict__ bias_t) {
  __shared__ float a_tab[40][68];
  __shared__ float c_tab[40][68];
  int gj = blockIdx.x;
  int t = threadIdx.x;
  int lane = t & 63;
  int wv_id = t >> 6;
  int row = lane & 15;
  int kgrp = lane >> 4;

  // build layer-1 tables: 2560 entries each, 10 per thread
  {
    const float* su_p = su_tab + gj * 40;
    const float* sv_p = sv_tab + gj * 40;
    for (int idx = t; idx < 2560; idx += 256) {
      int xi = idx >> 6, kk = idx & 63;
      a_tab[xi][kk] = fmaf(w0[2 * kk], su_p[xi], b0[kk]);
      c_tab[xi][kk] = w0[2 * kk + 1] * sv_p[xi];
    }
  }

  // B fragments: B[k][c] = w1[c][k]; hi/lo bf16 split (64 VGPRs)
  bf16x8 Bhi[4][2], Blo[4][2];
#pragma unroll
  for (int ct = 0; ct < 4; ++ct)
#pragma unroll
    for (int s = 0; s < 2; ++s)
#pragma unroll
      for (int e = 0; e < 8; ++e) {
        float wvv = w1[(ct * 16 + row) * 64 + s * 32 + kgrp * 8 + e];
        __bf16 h = (__bf16)wvv;
        Bhi[ct][s][e] = h;
        Blo[ct][s][e] = (__bf16)(wvv - (float)h);
      }
  float b1c[4], w2c[4];
#pragma unroll
  for (int ct = 0; ct < 4; ++ct) {
    b1c[ct] = b1v[ct * 16 + row];
    w2c[ct] = w2[ct * 16 + row];
  }
  float bb = b2[0];
  float* outp = bias_t + (size_t)gj * 1600;
  __syncthreads();

  // i = it*16 + row; track ix = i%40, iy = i/40 incrementally (step 16)
  int it0 = wv_id * 25;
  int i = it0 * 16 + row;
  int iy = i / 40;
  int ix = i - iy * 40;
  for (int it = it0; it < it0 + 25; ++it) {
    f32x4 acc[4];
#pragma unroll
    for (int ct = 0; ct < 4; ++ct) {
      acc[ct][0] = 0.f; acc[ct][1] = 0.f; acc[ct][2] = 0.f; acc[ct][3] = 0.f;
    }
#pragma unroll
    for (int s = 0; s < 2; ++s) {
      f32x4 av0 = *(const f32x4*)&a_tab[ix][s * 32 + kgrp * 8];
      f32x4 av1 = *(const f32x4*)&a_tab[ix][s * 32 + kgrp * 8 + 4];
      f32x4 cv0 = *(const f32x4*)&c_tab[iy][s * 32 + kgrp * 8];
      f32x4 cv1 = *(const f32x4*)&c_tab[iy][s * 32 + kgrp * 8 + 4];
      bf16x8 Ahi, Alo;
#pragma unroll
      for (int e = 0; e < 4; ++e) {
        float h0 = fmaxf(av0[e] + cv0[e], 0.f);
        __bf16 hh = (__bf16)h0;
        Ahi[e] = hh;
        Alo[e] = (__bf16)(h0 - (float)hh);
        float h1 = fmaxf(av1[e] + cv1[e], 0.f);
        __bf16 hh1 = (__bf16)h1;
        Ahi[e + 4] = hh1;
        Alo[e + 4] = (__bf16)(h1 - (float)hh1);
      }
#pragma unroll
      for (int ct = 0; ct < 4; ++ct) {
        acc[ct] = __builtin_amdgcn_mfma_f32_16x16x32_bf16(Ahi, Bhi[ct][s], acc[ct], 0, 0, 0);
        acc[ct] = __builtin_amdgcn_mfma_f32_16x16x32_bf16(Ahi, Blo[ct][s], acc[ct], 0, 0, 0);
        acc[ct] = __builtin_amdgcn_mfma_f32_16x16x32_bf16(Alo, Bhi[ct][s], acc[ct], 0, 0, 0);
      }
    }
    // epilogue: s2 = acc + b1; out_row = sum_c w2[c]*relu(s2[c]) + b2
    float part[4];
#pragma unroll
    for (int ri = 0; ri < 4; ++ri) {
      float s2 = 0.f;
#pragma unroll
      for (int ct = 0; ct < 4; ++ct) {
        float val = acc[ct][ri] + b1c[ct];
        s2 = fmaf(w2c[ct], fmaxf(val, 0.f), s2);
      }
      part[ri] = s2;
    }
#pragma unroll
    for (int m = 1; m < 16; m <<= 1) {
#pragma unroll
      for (int ri = 0; ri < 4; ++ri) part[ri] += __shfl_xor(part[ri], m);
    }
    if (row == 0) {
      f32x4 o;
      o[0] = part[0] + bb; o[1] = part[1] + bb;
      o[2] = part[2] + bb; o[3] = part[3] + bb;
      *(f32x4*)(outp + it * 16 + kgrp * 4) = o;
    }
    ix += 16;
    if (ix >= 40) { ix -= 40; ++iy; }
  }
}

// ---------------- fused attention, register-tiled (bias read transposed) ---
__global__ __launch_bounds__(256) void k_attn(
    const float* __restrict__ q, const float* __restrict__ k,
    const float* __restrict__ v, const float* __restrict__ bias_t,
    float* __restrict__ inner) {
  __shared__ float k_lds[64][104];
  __shared__ float v_lds[100][68];
  __shared__ float q_lds[64][36];
  __shared__ float s_lds[32][100];
  int h = blockIdx.x / 50;
  int i0 = (blockIdx.x % 50) * 32;
  int t = threadIdx.x;
  for (int idx = t; idx < 6400; idx += 256) {
    int d = idx / 100, j = idx - (idx / 100) * 100;
    k_lds[d][j] = k[(h * 64 + d) * 100 + j];
    v_lds[j][d] = v[(h * 64 + d) * 100 + j];
  }
  for (int idx = t; idx < 2048; idx += 256) {
    int d = idx >> 5, i = idx & 31;
    q_lds[d][i] = q[(h * 64 + d) * NP + i0 + i] * 0.125f;
  }
  __syncthreads();
  if (t < 200) {
    int ib = (t / 25) * 4, jb = (t % 25) * 4;
    float a[4][4];
#pragma unroll
    for (int ii = 0; ii < 4; ++ii)
#pragma unroll
      for (int jj = 0; jj < 4; ++jj) a[ii][jj] = 0.f;
    for (int d = 0; d < 64; ++d) {
      f32x4 qv = *(const f32x4*)&q_lds[d][ib];
      f32x4 kv4 = *(const f32x4*)&k_lds[d][jb];
#pragma unroll
      for (int ii = 0; ii < 4; ++ii)
#pragma unroll
        for (int jj = 0; jj < 4; ++jj)
          a[ii][jj] = fmaf(qv[ii], kv4[jj], a[ii][jj]);
    }
    const float* bcol = bias_t + (size_t)h * 100 * 1600;
#pragma unroll
    for (int jj = 0; jj < 4; ++jj) {
      f32x4 bv = *(const f32x4*)(bcol + (size_t)(jb + jj) * 1600 + i0 + ib);
#pragma unroll
      for (int ii = 0; ii < 4; ++ii)
        s_lds[ib + ii][jb + jj] = a[ii][jj] + bv[ii];
    }
  }
  __syncthreads();
  {
    int i = t >> 3, sub = t & 7;
    float m = -1e30f;
    for (int j = sub; j < 100; j += 8) m = fmaxf(m, s_lds[i][j]);
#pragma unroll
    for (int off = 1; off < 8; off <<= 1) m = fmaxf(m, __shfl_xor(m, off));
    float sum = 0.f;
    for (int j = sub; j < 100; j += 8) {
      float e = expf(s_lds[i][j] - m);
      s_lds[i][j] = e;
      sum += e;
    }
#pragma unroll
    for (int off = 1; off < 8; off <<= 1) sum += __shfl_xor(sum, off);
    float inv = 1.f / sum;
    for (int j = sub; j < 100; j += 8) s_lds[i][j] *= inv;
  }
  __syncthreads();
  {
    int ib = (t >> 4) * 2, db = (t & 15) * 4;
    float a0[4], a1[4];
#pragma unroll
    for (int dd = 0; dd < 4; ++dd) { a0[dd] = 0.f; a1[dd] = 0.f; }
    for (int j = 0; j < 100; ++j) {
      f32x4 vv = *(const f32x4*)&v_lds[j][db];
      float s0 = s_lds[ib][j], s1 = s_lds[ib + 1][j];
#pragma unroll
      for (int dd = 0; dd < 4; ++dd) {
        a0[dd] = fmaf(s0, vv[dd], a0[dd]);
        a1[dd] = fmaf(s1, vv[dd], a1[dd]);
      }
    }
#pragma unroll
    for (int dd = 0; dd < 4; ++dd) {
      f32x2 o; o[0] = a0[dd]; o[1] = a1[dd];
      *(f32x2*)&inner[(h * 64 + db + dd) * NP + i0 + ib] = o;
    }
  }
}

// ---------------- output projection 256x512 @ 512x1600 + bias --------------
__global__ __launch_bounds__(64) void k_proj(
    const float* __restrict__ inner, const float* __restrict__ w,
    const float* __restrict__ bo, float* __restrict__ out) {
  int ot = blockIdx.x / 25;
  int pt = blockIdx.x - ot * 25;
  int o0 = ot * 8;
  int p = pt * 64 + threadIdx.x;
  const float* w0r = w + o0 * 512;   // block-uniform -> scalar loads
  float acc[8];
#pragma unroll
  for (int oo = 0; oo < 8; ++oo) acc[oo] = 0.f;
#pragma unroll 8
  for (int c = 0; c < 512; ++c) {
    float xv = inner[c * NP + p];
#pragma unroll
    for (int oo = 0; oo < 8; ++oo)
      acc[oo] = fmaf(w0r[oo * 512 + c], xv, acc[oo]);
  }
#pragma unroll
  for (int oo = 0; oo < 8; ++oo)
    out[(o0 + oo) * NP + p] = acc[oo] + bo[o0 + oo];
}

extern "C" void kernel_launch(void* const* d_in, const int* in_sizes, int n_in,
                              void* d_out, int out_size, void* d_ws, size_t ws_size,
                              hipStream_t stream) {
  int L = in_sizes[1] / (512 * 32);
  int l = L - 1;
  const float* x      = (const float*)d_in[0];
  const float* wq     = (const float*)d_in[1]  + (size_t)l * 512 * 32;
  const float* wk     = (const float*)d_in[2]  + (size_t)l * 512 * 32;
  const float* wv     = (const float*)d_in[3]  + (size_t)l * 512 * 32;
  const float* w_off1 = (const float*)d_in[4]  + (size_t)l * 64 * 36;
  const float* b_off1 = (const float*)d_in[5]  + (size_t)l * 64;
  const float* w_off2 = (const float*)d_in[6]  + (size_t)l * 2 * 64;
  const float* cpb_w0 = (const float*)d_in[7]  + (size_t)l * 64 * 2;
  const float* cpb_b0 = (const float*)d_in[8]  + (size_t)l * 64;
  const float* cpb_w1 = (const float*)d_in[9]  + (size_t)l * 64 * 64;
  const float* cpb_b1 = (const float*)d_in[10] + (size_t)l * 64;
  const float* cpb_w2 = (const float*)d_in[11] + (size_t)l * 64;
  const float* cpb_b2 = (const float*)d_in[12] + (size_t)l * 1;
  const float* w_out  = (const float*)d_in[13] + (size_t)l * 256 * 512;
  const float* b_out  = (const float*)d_in[14] + (size_t)l * 256;
  float* out = (float*)d_out;

  float* ws = (float*)d_ws;
  float* q_ws    = ws;               // 819200
  float* off1    = ws + 819200;      // 51200
  float* k_ws    = ws + 870400;      // 51200
  float* v_ws    = ws + 921600;      // 51200
  float* bias_t  = ws + 972800;      // 1280000 (transposed [gj][i])
  float* inner   = ws + 2252800;     // 819200  (end 3,072,000 f = 12.29 MB)
  // su/sv tables (800*40 each) alias inner's head: written by k_off_pw_kv,
  // read by k_cpb_mfma, dead before k_attn overwrites inner.
  float* su_tab  = inner;            // 32000
  float* sv_tab  = inner + 32000;    // 32000

  k_conv1x1<<<320, 256, 0, stream>>>(x, wq, q_ws);
  k_off_dw<<<200, 256, 0, stream>>>(q_ws, w_off1, b_off1, off1);
  k_off_pw_kv<<<200, 256, 0, stream>>>(off1, w_off2, x, wk, wv,
                                       k_ws, v_ws, su_tab, sv_tab);
  k_cpb_mfma<<<800, 256, 0, stream>>>(su_tab, sv_tab, cpb_w0, cpb_b0,
                                      cpb_w1, cpb_b1, cpb_w2, cpb_b2, bias_t);
  k_attn<<<400, 256, 0, stream>>>(q_ws, k_ws, v_ws, bias_t, inner);
  k_proj<<<800, 64, 0, stream>>>(inner, w_out, b_out, out);
}

// Round 6
// 115.793 us; speedup vs baseline: 1.2305x; 1.2305x over previous
//
#include <hip/hip_runtime.h>
#include <math.h>

// BEV deformable attention encoder, layer l = L-1 only.
// Round 6: k_cpb_mfma v4 — fp16 2-term MFMA (B=w1 split hi/lo, A plain fp16;
// 16 MFMA/tile vs 24), fp16 LDS tables + packed f16 A-build, DPP epilogue
// reduce (no DS-pipe shfls), 1600 half-column blocks @ launch_bounds(256,4).
// k_attn: drop k/q LDS staging (L1) -> 40KB LDS -> 4 blocks/CU.
// k_proj: 400x256, 4 couts/thread.

#define NP 1600   // 40*40 query pixels
#define NJ 100    // 10*10 kv pixels

typedef _Float16 f16x8 __attribute__((ext_vector_type(8)));
typedef float  f32x4  __attribute__((ext_vector_type(4)));
typedef float  f32x2  __attribute__((ext_vector_type(2)));

template<int CTRL>
__device__ __forceinline__ float dpp_add(float x) {
  int y = __builtin_amdgcn_update_dpp(0, __builtin_bit_cast(int, x),
                                      CTRL, 0xf, 0xf, true);
  return x + __builtin_bit_cast(float, y);
}

// ---------------- grouped 1x1 conv (q): 8 groups, cin/g=32, cout/g=64 ------
__global__ __launch_bounds__(256) void k_conv1x1(
    const float* __restrict__ x, const float* __restrict__ w,
    float* __restrict__ out) {
  int b = blockIdx.x;
  int g = b / 40;
  int r = b - g * 40;
  int oc = r / 5;
  int p0 = (r - oc * 5) * 320;
  int co0 = g * 64 + oc * 8;
  const float* xg = x + g * 32 * NP;
  const float* wr = w + co0 * 32;   // block-uniform -> scalar loads
  for (int p = p0 + threadIdx.x; p < p0 + 320; p += 256) {
    float acc[8];
#pragma unroll
    for (int o = 0; o < 8; ++o) acc[o] = 0.f;
#pragma unroll
    for (int ci = 0; ci < 32; ++ci) {
      float xv = xg[ci * NP + p];
#pragma unroll
      for (int o = 0; o < 8; ++o) acc[o] = fmaf(wr[o * 32 + ci], xv, acc[o]);
    }
#pragma unroll
    for (int o = 0; o < 8; ++o) out[(co0 + o) * NP + p] = acc[o];
  }
}

// ------------- offset depthwise 6x6 s4 pad1 + bias + exact GELU ------------
__global__ __launch_bounds__(256) void k_off_dw(
    const float* __restrict__ q, const float* __restrict__ w1,
    const float* __restrict__ b1, float* __restrict__ off1) {
  int idx = blockIdx.x * 256 + threadIdx.x;   // 51200 exactly
  int j = idx % 100;
  int d = (idx / 100) & 63;
  int bg = idx / 6400;
  int oy = j / 10, ox = j - (j / 10) * 10;
  float acc = b1[d];
  const float* qc = q + (bg * 64 + d) * NP;
#pragma unroll
  for (int ky = 0; ky < 6; ++ky) {
    int iy = oy * 4 - 1 + ky;
    if (iy < 0 || iy >= 40) continue;
#pragma unroll
    for (int kx = 0; kx < 6; ++kx) {
      int ix = ox * 4 - 1 + kx;
      if (ix < 0 || ix >= 40) continue;
      acc = fmaf(w1[d * 36 + ky * 6 + kx], qc[iy * 40 + ix], acc);
    }
  }
  off1[idx] = 0.5f * acc * (1.0f + erff(acc * 0.70710678118654752440f));
}

// ------- fused: offset 1x1 + tanh*4 + grid + sample + k/v conv + tables ----
// One WAVE per (g,j): 800 waves = 200 blocks x 256.
__global__ __launch_bounds__(256) void k_off_pw_kv(
    const float* __restrict__ off1, const float* __restrict__ w2,
    const float* __restrict__ x, const float* __restrict__ wk,
    const float* __restrict__ wv, float* __restrict__ kout,
    float* __restrict__ vout, float* __restrict__ su_tab,
    float* __restrict__ sv_tab) {
  int lane = threadIdx.x & 63;
  int wid = blockIdx.x * 4 + (threadIdx.x >> 6);
  int g = wid / 100;
  int j = wid - g * 100;
  const float* wkr = wk + (g * 64 + lane) * 32;
  const float* wvr = wv + (g * 64 + lane) * 32;
  float wkreg[32], wvreg[32];
#pragma unroll
  for (int q4 = 0; q4 < 8; ++q4) {
    f32x4 a = *(const f32x4*)(wkr + q4 * 4);
    f32x4 b = *(const f32x4*)(wvr + q4 * 4);
#pragma unroll
    for (int e = 0; e < 4; ++e) { wkreg[q4 * 4 + e] = a[e]; wvreg[q4 * 4 + e] = b[e]; }
  }
  // pointwise offset conv + tanh*4
  float o = off1[(g * 64 + lane) * 100 + j];
  float px = w2[lane] * o, py = w2[64 + lane] * o;
#pragma unroll
  for (int m = 1; m < 64; m <<= 1) {
    px += __shfl_xor(px, m);
    py += __shfl_xor(py, m);
  }
  float ax = tanhf(px) * 4.f;
  float ay = tanhf(py) * 4.f;
  float vx = (float)(j - (j / 10) * 10) + ax;
  float vy = (float)(j / 10) + ay;
  float g0 = 2.f * vx / 9.f - 1.f;
  float g1 = 2.f * vy / 9.f - 1.f;
  // CPB signed-log coordinate tables: one entry per (gj, coord 0..39)
  if (lane < 40) {
    float qc = (float)lane * (2.f / 39.f) - 1.f;
    float u = qc - g0;
    float vv = qc - g1;
    su_tab[wid * 40 + lane] = copysignf(log1pf(fabsf(u)), u);
    sv_tab[wid * 40 + lane] = copysignf(log1pf(fabsf(vv)), vv);
  }
  // bilinear sample (uniform weights; lanes<32 gather), then k/v conv
  float gx = ((g0 + 1.f) * 40.f - 1.f) * 0.5f;
  float gy = ((g1 + 1.f) * 40.f - 1.f) * 0.5f;
  float x0f = floorf(gx), y0f = floorf(gy);
  float wx = gx - x0f, wy = gy - y0f;
  bool mx0 = (x0f >= 0.f) && (x0f <= 39.f);
  bool mx1 = (x0f + 1.f >= 0.f) && (x0f + 1.f <= 39.f);
  bool my0 = (y0f >= 0.f) && (y0f <= 39.f);
  bool my1 = (y0f + 1.f >= 0.f) && (y0f + 1.f <= 39.f);
  int ix0 = (int)fminf(fmaxf(x0f, 0.f), 39.f);
  int ix1 = (int)fminf(fmaxf(x0f + 1.f, 0.f), 39.f);
  int iy0 = (int)fminf(fmaxf(y0f, 0.f), 39.f);
  int iy1 = (int)fminf(fmaxf(y0f + 1.f, 0.f), 39.f);
  float w00 = (1.f - wx) * (1.f - wy) * ((mx0 && my0) ? 1.f : 0.f);
  float w10 = wx * (1.f - wy) * ((mx1 && my0) ? 1.f : 0.f);
  float w01 = (1.f - wx) * wy * ((mx0 && my1) ? 1.f : 0.f);
  float w11 = wx * wy * ((mx1 && my1) ? 1.f : 0.f);
  int b00 = iy0 * 40 + ix0, b10 = iy0 * 40 + ix1;
  int b01 = iy1 * 40 + ix0, b11 = iy1 * 40 + ix1;
  float kvc = 0.f;
  if (lane < 32) {
    const float* xc = x + (g * 32 + lane) * NP;
    kvc = w00 * xc[b00] + w10 * xc[b10] + w01 * xc[b01] + w11 * xc[b11];
  }
  float kacc = 0.f, vacc = 0.f;
#pragma unroll
  for (int c = 0; c < 32; ++c) {
    float kvb = __shfl(kvc, c);
    kacc = fmaf(wkreg[c], kvb, kacc);
    vacc = fmaf(wvreg[c], kvb, vacc);
  }
  kout[(g * 64 + lane) * 100 + j] = kacc;
  vout[(g * 64 + lane) * 100 + j] = vacc;
}

// ---------------- CPB bias MLP v4: fp16 2-term MFMA + DPP epilogue ---------
// 1600 blocks: gj = b>>1, half-column (50 tiles) each; 4 waves/block.
// LDS fp16 tables a16[ix][k], c16[iy][k]; A = relu(a+c) in packed fp16.
// D = A*(Bhi+Blo), B = w1 split hi/lo fp16 (B exact, A fp16 quantized).
__global__ __launch_bounds__(256, 4) void k_cpb_mfma(
    const float* __restrict__ su_tab, const float* __restrict__ sv_tab,
    const float* __restrict__ w0, const float* __restrict__ b0,
    const float* __restrict__ w1, const float* __restrict__ b1v,
    const float* __restrict__ w2, const float* __restrict__ b2,
    float* __restrict__ bias_t) {
  __shared__ _Float16 a16[40][72];
  __shared__ _Float16 c16[40][72];
  int gj = blockIdx.x >> 1;
  int half = blockIdx.x & 1;
  int t = threadIdx.x;
  int lane = t & 63;
  int row = lane & 15;
  int kgrp = lane >> 4;

  // build fp16 layer-1 tables (both halves build the full 40x64)
  {
    const float* su_p = su_tab + gj * 40;
    const float* sv_p = sv_tab + gj * 40;
    for (int idx = t; idx < 2560; idx += 256) {
      int xi = idx >> 6, kk = idx & 63;
      a16[xi][kk] = (_Float16)fmaf(w0[2 * kk], su_p[xi], b0[kk]);
      c16[xi][kk] = (_Float16)(w0[2 * kk + 1] * sv_p[xi]);
    }
  }

  // B fragments: B[k][c] = w1[c][k]; fp16 hi/lo split (exact B)
  f16x8 Bhi[4][2], Blo[4][2];
#pragma unroll
  for (int ct = 0; ct < 4; ++ct)
#pragma unroll
    for (int s = 0; s < 2; ++s)
#pragma unroll
      for (int e = 0; e < 8; ++e) {
        float wvv = w1[(ct * 16 + row) * 64 + s * 32 + kgrp * 8 + e];
        _Float16 h = (_Float16)wvv;
        Bhi[ct][s][e] = h;
        Blo[ct][s][e] = (_Float16)(wvv - (float)h);
      }
  float b1c[4], w2c[4];
#pragma unroll
  for (int ct = 0; ct < 4; ++ct) {
    b1c[ct] = b1v[ct * 16 + row];
    w2c[ct] = w2[ct * 16 + row];
  }
  float bb = b2[0];
  float* outp = bias_t + (size_t)gj * 1600;
  __syncthreads();

  // wave wv (0..7 across the column's 2 blocks) -> 12 or 13 tiles of 100
  int wv = half * 4 + (t >> 6);
  int it0 = wv * 12 + (wv < 4 ? wv : 4);
  int cnt = (wv < 4) ? 13 : 12;
  int i = it0 * 16 + row;
  int iy = i / 40;
  int ix = i - iy * 40;
  f16x8 zero8 = {};
  for (int it = it0; it < it0 + cnt; ++it) {
    f32x4 acc[4];
#pragma unroll
    for (int ct = 0; ct < 4; ++ct) {
      acc[ct][0] = 0.f; acc[ct][1] = 0.f; acc[ct][2] = 0.f; acc[ct][3] = 0.f;
    }
#pragma unroll
    for (int s = 0; s < 2; ++s) {
      f16x8 av = *(const f16x8*)&a16[ix][s * 32 + kgrp * 8];
      f16x8 cv = *(const f16x8*)&c16[iy][s * 32 + kgrp * 8];
      f16x8 A = __builtin_elementwise_max(av + cv, zero8);   // v_pk_add/max_f16
#pragma unroll
      for (int ct = 0; ct < 4; ++ct) {
        acc[ct] = __builtin_amdgcn_mfma_f32_16x16x32_f16(A, Bhi[ct][s], acc[ct], 0, 0, 0);
        acc[ct] = __builtin_amdgcn_mfma_f32_16x16x32_f16(A, Blo[ct][s], acc[ct], 0, 0, 0);
      }
    }
    // epilogue: s2 = acc + b1; out_row = sum_c w2[c]*relu(s2[c]) + b2
    float part[4];
#pragma unroll
    for (int ri = 0; ri < 4; ++ri) {
      float s2 = 0.f;
#pragma unroll
      for (int ct = 0; ct < 4; ++ct) {
        float val = acc[ct][ri] + b1c[ct];
        s2 = fmaf(w2c[ct], fmaxf(val, 0.f), s2);
      }
      part[ri] = s2;
    }
    // 16-lane sum via DPP (VALU only): xor1, xor2, half-mirror, mirror
#pragma unroll
    for (int ri = 0; ri < 4; ++ri) {
      part[ri] = dpp_add<0xB1>(part[ri]);    // quad_perm [1,0,3,2]
      part[ri] = dpp_add<0x4E>(part[ri]);    // quad_perm [2,3,0,1]
      part[ri] = dpp_add<0x141>(part[ri]);   // row_half_mirror
      part[ri] = dpp_add<0x140>(part[ri]);   // row_mirror
    }
    if (row == 0) {
      f32x4 o;
      o[0] = part[0] + bb; o[1] = part[1] + bb;
      o[2] = part[2] + bb; o[3] = part[3] + bb;
      *(f32x4*)(outp + it * 16 + kgrp * 4) = o;
    }
    ix += 16;
    if (ix >= 40) { ix -= 40; ++iy; }
  }
}

// ---------------- fused attention: v in LDS, q/k via L1, reg-tiled ---------
__global__ __launch_bounds__(256) void k_attn(
    const float* __restrict__ q, const float* __restrict__ k,
    const float* __restrict__ v, const float* __restrict__ bias_t,
    float* __restrict__ inner) {
  __shared__ float v_lds[100][68];   // [j][d]
  __shared__ float s_lds[32][100];
  int h = blockIdx.x / 50;
  int i0 = (blockIdx.x % 50) * 32;
  int t = threadIdx.x;
  for (int idx = t; idx < 6400; idx += 256) {
    int d = idx / 100, j = idx - (idx / 100) * 100;
    v_lds[j][d] = v[(h * 64 + d) * 100 + j];
  }
  __syncthreads();
  // sim: 4x4 register tiles; q,k f32x4 straight from L1-resident slices
  if (t < 200) {
    int ib = (t / 25) * 4, jb = (t % 25) * 4;
    const float* qp = q + h * 64 * NP + i0 + ib;
    const float* kp = k + h * 64 * 100 + jb;
    float a[4][4];
#pragma unroll
    for (int ii = 0; ii < 4; ++ii)
#pragma unroll
      for (int jj = 0; jj < 4; ++jj) a[ii][jj] = 0.f;
#pragma unroll 8
    for (int d = 0; d < 64; ++d) {
      f32x4 qv = *(const f32x4*)(qp + d * NP);
      f32x4 kv4 = *(const f32x4*)(kp + d * 100);
#pragma unroll
      for (int ii = 0; ii < 4; ++ii)
#pragma unroll
        for (int jj = 0; jj < 4; ++jj)
          a[ii][jj] = fmaf(qv[ii], kv4[jj], a[ii][jj]);
    }
    const float* bcol = bias_t + (size_t)h * 100 * 1600;
#pragma unroll
    for (int jj = 0; jj < 4; ++jj) {
      f32x4 bv = *(const f32x4*)(bcol + (size_t)(jb + jj) * 1600 + i0 + ib);
#pragma unroll
      for (int ii = 0; ii < 4; ++ii)
        s_lds[ib + ii][jb + jj] = fmaf(a[ii][jj], 0.125f, bv[ii]);
    }
  }
  __syncthreads();
  {
    int i = t >> 3, sub = t & 7;
    float m = -1e30f;
    for (int j = sub; j < 100; j += 8) m = fmaxf(m, s_lds[i][j]);
#pragma unroll
    for (int off = 1; off < 8; off <<= 1) m = fmaxf(m, __shfl_xor(m, off));
    float sum = 0.f;
    for (int j = sub; j < 100; j += 8) {
      float e = expf(s_lds[i][j] - m);
      s_lds[i][j] = e;
      sum += e;
    }
#pragma unroll
    for (int off = 1; off < 8; off <<= 1) sum += __shfl_xor(sum, off);
    float inv = 1.f / sum;
    for (int j = sub; j < 100; j += 8) s_lds[i][j] *= inv;
  }
  __syncthreads();
  {
    int ib = (t >> 4) * 2, db = (t & 15) * 4;
    float a0[4], a1[4];
#pragma unroll
    for (int dd = 0; dd < 4; ++dd) { a0[dd] = 0.f; a1[dd] = 0.f; }
    for (int j = 0; j < 100; ++j) {
      f32x4 vv = *(const f32x4*)&v_lds[j][db];
      float s0 = s_lds[ib][j], s1 = s_lds[ib + 1][j];
#pragma unroll
      for (int dd = 0; dd < 4; ++dd) {
        a0[dd] = fmaf(s0, vv[dd], a0[dd]);
        a1[dd] = fmaf(s1, vv[dd], a1[dd]);
      }
    }
#pragma unroll
    for (int dd = 0; dd < 4; ++dd) {
      f32x2 o; o[0] = a0[dd]; o[1] = a1[dd];
      *(f32x2*)&inner[(h * 64 + db + dd) * NP + i0 + ib] = o;
    }
  }
}

// ---------------- output projection 256x512 @ 512x1600 + bias --------------
// 400 blocks x 256: block = (16 couts) x (64 p); thread = 4 couts x 1 p.
__global__ __launch_bounds__(256) void k_proj(
    const float* __restrict__ inner, const float* __restrict__ w,
    const float* __restrict__ bo, float* __restrict__ out) {
  int ot = blockIdx.x / 25;
  int pt = blockIdx.x - ot * 25;
  int t = threadIdx.x;
  int quad = __builtin_amdgcn_readfirstlane(t >> 6);  // wave-uniform
  int o0 = ot * 16 + quad * 4;
  int p = pt * 64 + (t & 63);
  const float* w0r = w + o0 * 512;   // wave-uniform -> scalar loads
  float a0 = 0.f, a1 = 0.f, a2 = 0.f, a3 = 0.f;
#pragma unroll 8
  for (int c = 0; c < 512; ++c) {
    float xv = inner[c * NP + p];
    a0 = fmaf(w0r[c], xv, a0);
    a1 = fmaf(w0r[512 + c], xv, a1);
    a2 = fmaf(w0r[1024 + c], xv, a2);
    a3 = fmaf(w0r[1536 + c], xv, a3);
  }
  out[(o0 + 0) * NP + p] = a0 + bo[o0 + 0];
  out[(o0 + 1) * NP + p] = a1 + bo[o0 + 1];
  out[(o0 + 2) * NP + p] = a2 + bo[o0 + 2];
  out[(o0 + 3) * NP + p] = a3 + bo[o0 + 3];
}

extern "C" void kernel_launch(void* const* d_in, const int* in_sizes, int n_in,
                              void* d_out, int out_size, void* d_ws, size_t ws_size,
                              hipStream_t stream) {
  int L = in_sizes[1] / (512 * 32);
  int l = L - 1;
  const float* x      = (const float*)d_in[0];
  const float* wq     = (const float*)d_in[1]  + (size_t)l * 512 * 32;
  const float* wk     = (const float*)d_in[2]  + (size_t)l * 512 * 32;
  const float* wv     = (const float*)d_in[3]  + (size_t)l * 512 * 32;
  const float* w_off1 = (const float*)d_in[4]  + (size_t)l * 64 * 36;
  const float* b_off1 = (const float*)d_in[5]  + (size_t)l * 64;
  const float* w_off2 = (const float*)d_in[6]  + (size_t)l * 2 * 64;
  const float* cpb_w0 = (const float*)d_in[7]  + (size_t)l * 64 * 2;
  const float* cpb_b0 = (const float*)d_in[8]  + (size_t)l * 64;
  const float* cpb_w1 = (const float*)d_in[9]  + (size_t)l * 64 * 64;
  const float* cpb_b1 = (const float*)d_in[10] + (size_t)l * 64;
  const float* cpb_w2 = (const float*)d_in[11] + (size_t)l * 64;
  const float* cpb_b2 = (const float*)d_in[12] + (size_t)l * 1;
  const float* w_out  = (const float*)d_in[13] + (size_t)l * 256 * 512;
  const float* b_out  = (const float*)d_in[14] + (size_t)l * 256;
  float* out = (float*)d_out;

  float* ws = (float*)d_ws;
  float* q_ws    = ws;               // 819200
  float* off1    = ws + 819200;      // 51200
  float* k_ws    = ws + 870400;      // 51200
  float* v_ws    = ws + 921600;      // 51200
  float* bias_t  = ws + 972800;      // 1280000 (transposed [gj][i])
  float* inner   = ws + 2252800;     // 819200  (end 3,072,000 f = 12.29 MB)
  // su/sv tables (800*40 each) alias inner's head: written by k_off_pw_kv,
  // read by k_cpb_mfma, dead before k_attn overwrites inner.
  float* su_tab  = inner;            // 32000
  float* sv_tab  = inner + 32000;    // 32000

  k_conv1x1<<<320, 256, 0, stream>>>(x, wq, q_ws);
  k_off_dw<<<200, 256, 0, stream>>>(q_ws, w_off1, b_off1, off1);
  k_off_pw_kv<<<200, 256, 0, stream>>>(off1, w_off2, x, wk, wv,
                                       k_ws, v_ws, su_tab, sv_tab);
  k_cpb_mfma<<<1600, 256, 0, stream>>>(su_tab, sv_tab, cpb_w0, cpb_b0,
                                       cpb_w1, cpb_b1, cpb_w2, cpb_b2, bias_t);
  k_attn<<<400, 256, 0, stream>>>(q_ws, k_ws, v_ws, bias_t, inner);
  k_proj<<<400, 256, 0, stream>>>(inner, w_out, b_out, out);
}